// Round 9
// baseline (381.409 us; speedup 1.0000x reference)
//
#include <hip/hip_runtime.h>

#define BN      64
#define KCLS    3
#define PPIX    147456
#define NB1     4096
#define NBR     2048
#define BPR     36               // blocks per row
#define PXB     4096             // pixels per block
#define PXT     16               // pixels per thread
#define NBLK    (BN * BPR)       // 2304
#define CANDCAP 2048             // per-block candidate slots (expect ~550)

// ---------------- workspace layout (bytes) ----------------
static const size_t OFF_BSUM = 0;                                  // NBLK*8
static const size_t OFF_BCNT = OFF_BSUM + (size_t)NBLK * 8;        // NBLK*4
static const size_t OFF_BCC  = OFF_BCNT + (size_t)NBLK * 4;        // NBLK*4
static const size_t OFF_ACC  = OFF_BCC + (size_t)NBLK * 4;         // double
static const size_t OFF_D2   = OFF_ACC + 8;                        // u32
static const size_t OFF_CAND = OFF_D2 + 8;                         // NBLK*CANDCAP*4

__device__ __forceinline__ unsigned topk_count(const int* sp_ptr) {
    double sp = (double)sp_ptr[0];
    if (sp > 1.0) sp = 1.0;
    return (unsigned)(sp * 0.15 * (double)PPIX + (1.0 - sp) * (double)PPIX);
}

__device__ __forceinline__ float sel_nll(int t, float a, float b, float c) {
    float lp = (t == 0) ? a : ((t == 1) ? b : ((t == 2) ? c : 0.0f));
    return fmaxf(-lp, 0.0f);   // nll >= 0; kill -0.0
}

// ------------- kernel 1: burst-load stream + self-bracket + compact ---------
__global__ __launch_bounds__(256, 4) void k_stream(
    const float* __restrict__ in, const int* __restrict__ tgt, const int* __restrict__ sp,
    double* __restrict__ bsum, unsigned* __restrict__ bcnt, unsigned* __restrict__ bccnt,
    float* __restrict__ cand, double* __restrict__ accum, unsigned* __restrict__ done2)
{
    __shared__ unsigned hist[NB1];     // 16 KB
    __shared__ unsigned cred[256];
    __shared__ double   dred[256];
    __shared__ int s_bL, s_bH, lcnt;

    const int tid   = threadIdx.x;
    const int row   = blockIdx.x / BPR;
    const int chunk = blockIdx.x % BPR;

    if (blockIdx.x == 0 && tid == 0) { accum[0] = 0.0; done2[0] = 0u; } // used only in kernel 2

    for (int i = tid; i < NB1; i += 256) hist[i] = 0u;
    if (tid == 0) { s_bL = 0; s_bH = NB1 - 1; lcnt = 0; }
    __syncthreads();

    const float4* p0 = (const float4*)(in + (size_t)row * KCLS * PPIX);
    const float4* p1 = p0 + PPIX / 4;
    const float4* p2 = p1 + PPIX / 4;
    const int4*   t4 = (const int4*)(tgt + (size_t)row * PPIX);
    const int base = chunk * (PXB / 4);

    // ---- burst: issue all 16 independent loads before any use ----
    int4   T[4]; float4 A[4], B[4], C[4];
    #pragma unroll
    for (int b = 0; b < 4; ++b) T[b] = t4[base + b * 256 + tid];
    #pragma unroll
    for (int b = 0; b < 4; ++b) A[b] = p0[base + b * 256 + tid];
    #pragma unroll
    for (int b = 0; b < 4; ++b) B[b] = p1[base + b * 256 + tid];
    #pragma unroll
    for (int b = 0; b < 4; ++b) C[b] = p2[base + b * 256 + tid];

    float v[PXT];
    #pragma unroll
    for (int b = 0; b < 4; ++b) {
        v[4*b+0] = sel_nll(T[b].x, A[b].x, B[b].x, C[b].x);
        v[4*b+1] = sel_nll(T[b].y, A[b].y, B[b].y, C[b].y);
        v[4*b+2] = sel_nll(T[b].z, A[b].z, B[b].z, C[b].z);
        v[4*b+3] = sel_nll(T[b].w, A[b].w, B[b].w, C[b].w);
    }
    #pragma unroll
    for (int i = 0; i < PXT; ++i) atomicAdd(&hist[__float_as_uint(v[i]) >> 19], 1u);
    __syncthreads();

    // ---- local descending scan: bracket this block's 4096 values ----
    const unsigned k = topk_count(sp);
    const float p  = (float)k / (float)PPIX;
    const float mu = (float)PXB * p;
    const float sg = sqrtf((float)PXB * p * (1.0f - p));
    const float marg = 10.0f * sg + 8.0f;
    const float tH = mu - marg;            // definite-top rank bound
    const float tL = mu + marg;            // definite-out rank bound

    unsigned cl[16]; unsigned cacc = 0;
    const int b0 = tid * 16;
    #pragma unroll
    for (int i = 0; i < 16; ++i) {
        cl[i] = hist[NB1 - 1 - (b0 + i)];
        cacc += cl[i];
    }
    cred[tid] = cacc;
    __syncthreads();
    for (int off = 1; off < 256; off <<= 1) {
        unsigned t2 = (tid >= off) ? cred[tid - off] : 0u;
        __syncthreads();
        cred[tid] += t2;
        __syncthreads();
    }
    {
        unsigned cum = tid ? cred[tid - 1] : 0u;
        #pragma unroll
        for (int i = 0; i < 16; ++i) {
            const unsigned cb = cl[i];
            const float fc = (float)cum, fe = (float)(cum + cb);
            if (fc < tH && fe >= tH) s_bH = NB1 - 1 - (b0 + i);
            if (fc < tL && fe >= tL) s_bL = NB1 - 1 - (b0 + i);
            cum += cb;
        }
    }
    __syncthreads();

    // ---- classify from registers ----
    const unsigned hi = ((unsigned)s_bH + 1u) << 19;   // u >= hi: definitely top-k
    const unsigned lo = ((unsigned)s_bL) << 19;        // [lo,hi): candidate
    double acc = 0.0; unsigned cab = 0;
    float* cr = cand + (size_t)blockIdx.x * CANDCAP;
    #pragma unroll
    for (int i = 0; i < PXT; ++i) {
        const unsigned u = __float_as_uint(v[i]);
        if (u >= hi) {
            acc += (double)v[i]; ++cab;
        } else if (u >= lo) {
            const int pos = atomicAdd(&lcnt, 1);
            if (pos < CANDCAP) cr[pos] = v[i];
        }
    }
    dred[tid] = acc; cred[tid] = cab;
    __syncthreads();
    for (int s = 128; s > 0; s >>= 1) {
        if (tid < s) { dred[tid] += dred[tid + s]; cred[tid] += cred[tid + s]; }
        __syncthreads();
    }
    if (tid == 0) {
        bsum[blockIdx.x]  = dred[0];
        bcnt[blockIdx.x]  = cred[0];
        bccnt[blockIdx.x] = (unsigned)((lcnt > CANDCAP) ? CANDCAP : lcnt);
    }
}

// ------------- kernel 2: per-row exact resolve (bracket-start) + mean -------
__global__ __launch_bounds__(256) void k_resolve(
    const float* __restrict__ cand, const unsigned* __restrict__ bccnt,
    const unsigned* __restrict__ bcnt, const double* __restrict__ bsum,
    const int* __restrict__ sp, double* __restrict__ accum,
    unsigned* __restrict__ done2, float* __restrict__ out)
{
    __shared__ unsigned hc[NBR];
    __shared__ unsigned cred[256];
    __shared__ double   dred[256];
    __shared__ int  pseg[BPR + 1];
    __shared__ int  s_t, s_r;

    const int row = blockIdx.x, tid = threadIdx.x;
    const unsigned k = topk_count(sp);

    // row totals + segment prefix
    {
        double a = 0.0; unsigned c = 0;
        for (int s = tid; s < BPR; s += 256) {
            a += bsum[row * BPR + s];
            c += bcnt[row * BPR + s];
        }
        dred[tid] = a; cred[tid] = c;
        __syncthreads();
        for (int s = 128; s > 0; s >>= 1) {
            if (tid < s) { dred[tid] += dred[tid + s]; cred[tid] += cred[tid + s]; }
            __syncthreads();
        }
        if (tid == 0) {
            int run = 0;
            pseg[0] = 0;
            for (int s = 0; s < BPR; ++s) { run += (int)bccnt[row * BPR + s]; pseg[s + 1] = run; }
        }
        __syncthreads();
    }
    const double S = dred[0];
    const unsigned above = cred[0];
    const int n = pseg[BPR];
    long rr = (long)k - (long)above;
    if (rr < 1) rr = 1;
    if (rr > n) rr = n;
    __syncthreads();

    const float* crow = cand + (size_t)row * BPR * CANDCAP;
    // flattened access: global idx g -> segment via binary search on pseg
    #define CAND_AT(g, dst) {                                              \
        int lo_ = 0, hi_ = BPR;                                            \
        while (hi_ - lo_ > 1) { int m_ = (lo_ + hi_) >> 1;                 \
            if ((g) >= pseg[m_]) lo_ = m_; else hi_ = m_; }                \
        dst = crow[(size_t)lo_ * CANDCAP + ((g) - pseg[lo_])]; }

    double tail = 0.0;
    if (n > 0) {
        // ---- pass 0: min/max of candidate bit patterns ----
        unsigned umin = 0xFFFFFFFFu, umax = 0u;
        for (int g = tid; g < n; g += 256) {
            float x; CAND_AT(g, x);
            const unsigned u = __float_as_uint(x);
            umin = (u < umin) ? u : umin;
            umax = (u > umax) ? u : umax;
        }
        cred[tid] = umin;
        __syncthreads();
        for (int s = 128; s > 0; s >>= 1) {
            if (tid < s) { const unsigned o = cred[tid + s]; if (o < cred[tid]) cred[tid] = o; }
            __syncthreads();
        }
        umin = cred[0];
        __syncthreads();
        cred[tid] = umax;
        __syncthreads();
        for (int s = 128; s > 0; s >>= 1) {
            if (tid < s) { const unsigned o = cred[tid + s]; if (o > cred[tid]) cred[tid] = o; }
            __syncthreads();
        }
        umax = cred[0];
        __syncthreads();

        // ---- narrowing from the actual data range (bins well spread) ----
        unsigned clo = umin, cbhi = umax + 1u;
        for (;;) {
            const unsigned width = cbhi - clo;
            const bool exact = (width <= (unsigned)NBR);
            int s2 = 0;
            if (!exact) {
                const unsigned w1 = width - 1u;
                const int m = 32 - __clz((int)w1);   // w1 < 2^m
                s2 = m - 11;                          // (w1 >> s2) < 2048
            }
            for (int i = tid; i < NBR; i += 256) hc[i] = 0u;
            __syncthreads();
            for (int g = tid; g < n; g += 256) {
                float x; CAND_AT(g, x);
                const unsigned u = __float_as_uint(x);
                if (u >= clo && u < cbhi) atomicAdd(&hc[(u - clo) >> s2], 1u);
            }
            __syncthreads();

            unsigned cl[8]; unsigned cacc = 0;
            const int b0 = tid * 8;
            #pragma unroll
            for (int i = 0; i < 8; ++i) { cl[i] = hc[NBR - 1 - (b0 + i)]; cacc += cl[i]; }
            cred[tid] = cacc;
            __syncthreads();
            for (int off = 1; off < 256; off <<= 1) {
                unsigned t2 = (tid >= off) ? cred[tid - off] : 0u;
                __syncthreads();
                cred[tid] += t2;
                __syncthreads();
            }
            long cum = tid ? (long)cred[tid - 1] : 0;
            #pragma unroll
            for (int i = 0; i < 8; ++i) {
                const long cb = (long)cl[i];
                if (cum < rr && cum + cb >= rr) {   // exactly one (thread,i)
                    s_t = NBR - 1 - (b0 + i);
                    s_r = (int)(rr - cum);
                }
                cum += cb;
            }
            __syncthreads();
            if (exact) break;
            const unsigned nlo = clo + ((unsigned)s_t << s2);
            unsigned nhi = nlo + (1u << s2);
            if (nhi > cbhi) nhi = cbhi;
            clo = nlo; cbhi = nhi;
            rr = s_r;
            __syncthreads();
        }

        // ---- sum pass: strictly above threshold + tie copies ----
        const unsigned tbits = clo + (unsigned)s_t;
        double acc = 0.0;
        for (int g = tid; g < n; g += 256) {
            float x; CAND_AT(g, x);
            if (__float_as_uint(x) > tbits) acc += (double)x;
        }
        dred[tid] = acc;
        __syncthreads();
        for (int s = 128; s > 0; s >>= 1) {
            if (tid < s) dred[tid] += dred[tid + s];
            __syncthreads();
        }
        if (tid == 0)
            tail = dred[0] + (double)s_r * (double)__uint_as_float(tbits);
    }
    #undef CAND_AT

    if (tid == 0) {
        atomicAdd(accum, S + tail);
        __threadfence();
        const unsigned o2 = atomicAdd(done2, 1u);
        if (o2 == BN - 1) {
            __threadfence();
            const double a = atomicAdd(accum, 0.0);   // coherent read-back
            out[0] = (float)(a / ((double)BN * (double)k));
        }
    }
}

extern "C" void kernel_launch(void* const* d_in, const int* in_sizes, int n_in,
                              void* d_out, int out_size, void* d_ws, size_t ws_size,
                              hipStream_t stream)
{
    const float* in  = (const float*)d_in[0];
    const int*   tgt = (const int*)d_in[1];
    const int*   sp  = (const int*)d_in[2];

    char* ws = (char*)d_ws;
    double*   bsum  = (double*)(ws + OFF_BSUM);
    unsigned* bcnt  = (unsigned*)(ws + OFF_BCNT);
    unsigned* bccnt = (unsigned*)(ws + OFF_BCC);
    double*   accum = (double*)(ws + OFF_ACC);
    unsigned* done2 = (unsigned*)(ws + OFF_D2);
    float*    cand  = (float*)(ws + OFF_CAND);

    k_stream <<<NBLK, 256, 0, stream>>>(in, tgt, sp, bsum, bcnt, bccnt, cand, accum, done2);
    k_resolve<<<BN, 256, 0, stream>>>(cand, bccnt, bcnt, bsum, sp, accum, done2, (float*)d_out);
}